// Round 5
// baseline (150.346 us; speedup 1.0000x reference)
//
#include <hip/hip_runtime.h>

// GNN layer: out = segment_sum(nf[src], dst) @ W.T + b
// N=50000, E=800000, D=128.
// R18: async gather via global_load_lds (VGPR-free MLP). R15/R16/R17 all
// failed the same way: hipcc sinks register-result loads to their uses
// (VGPR pinned 32..52), so per-wave MLP stays ~1-2 and the gather is
// latency-bound (~1.6TB/s on the L2-miss path). global_load_lds has no
// VGPR result -> nothing to serialize; depth controlled by counted vmcnt
// (never 0 mid-loop, T3/T4 pattern). New shape: BS=64, 512 threads,
// 782 buckets. Phase B: each wave streams its contiguous 8-node CSR
// segment through a 4KB LDS staging ring, chunks of 8 edges
// (2 x global_load_lds_dwordx4), depth-2: issue c+2 after consuming c,
// wait vmcnt(2). Consume: 64 lanes x ds_read_b32 (2 dims/lane), uniform
// node-boundary flush to tile. 57.7KB LDS -> 2 blocks/CU, 16 waves/CU,
// 32-64KB/CU gather in flight (vs ~1.6KB before).

constexpr int NN = 50000;
constexpr int NE = 800000;
constexpr int D  = 128;

constexpr int BS   = 64;                       // nodes per bucket
constexpr int NB   = (NN + BS - 1) / BS;       // 782 buckets
constexpr int EPB  = 4096;                     // edges per producer block
constexpr int NSB  = (NE + EPB - 1) / EPB;     // 196 producer blocks
constexpr int CAP  = 2048;                     // per-bucket edge cap (avg 1023)

constexpr int AROWU = 136;                     // tile row stride (ushorts)

typedef __attribute__((ext_vector_type(8))) short bf16x8;
typedef __attribute__((ext_vector_type(4))) float f32x4;
typedef __attribute__((ext_vector_type(2))) float f32x2;

__device__ inline unsigned short f2bf(float f) {           // RNE
    unsigned u = __float_as_uint(f);
    return (unsigned short)((u + 0x7fffu + ((u >> 16) & 1u)) >> 16);
}
__device__ inline float bflo(unsigned v) { return __uint_as_float(v << 16); }
__device__ inline float bfhi(unsigned v) { return __uint_as_float(v & 0xffff0000u); }

__device__ inline int wscan(int v) {           // wave-inclusive scan (64)
    #pragma unroll
    for (int o = 1; o < 64; o <<= 1) {
        int u = __shfl_up(v, o);
        if ((int)(threadIdx.x & 63) >= o) v += u;
    }
    return v;
}

// async 16B/lane gather into LDS (linear dest: base + lane*16)
__device__ __forceinline__ void gl_lds16(const unsigned* g, unsigned* l) {
    __builtin_amdgcn_global_load_lds(
        (const __attribute__((address_space(1))) unsigned*)g,
        (__attribute__((address_space(3))) unsigned*)l, 16, 0, 0);
}
#define WAITVM2() { asm volatile("s_waitcnt vmcnt(2)" ::: "memory"); \
                    __builtin_amdgcn_sched_barrier(0); }
#define WAITVM0() { asm volatile("s_waitcnt vmcnt(0)" ::: "memory"); \
                    __builtin_amdgcn_sched_barrier(0); }

// ---- 1. fused prep (bf16 cvt) + bucket-sort partition ---------------------
constexpr int NF4 = NN * D / 4;                           // 1,600,000
constexpr int W4  = D * D / 4;                            // 4,096
constexpr int NBLK_P = (NF4 + W4 + 511) / 512;            // 3134
constexpr int GRID_A = NSB + NBLK_P;

__global__ __launch_bounds__(512) void k_prep_bucket(
    const float* __restrict__ nf, const float* __restrict__ W,
    const int* __restrict__ ei,
    ushort* __restrict__ nfh, ushort* __restrict__ Wh,
    ushort* __restrict__ offs, unsigned* __restrict__ buf)
{
    __shared__ int hist[NB], cur[NB];              // 6256 B
    __shared__ int wsum[8];
    __shared__ unsigned spk[EPB];                  // 16384 B
    const int t = threadIdx.x, lane = t & 63, w = t >> 6;

    if (blockIdx.x < NSB) {
        const int blk = blockIdx.x;
        const int e0  = blk * EPB;
        int cnt = NE - e0; if (cnt > EPB) cnt = EPB;

        for (int i = t; i < NB; i += 512) hist[i] = 0;
        __syncthreads();

        unsigned pk[8];
        #pragma unroll
        for (int j = 0; j < 8; ++j) {
            int idx = j * 512 + t;
            if (idx < cnt) {
                int e = e0 + idx;
                unsigned s = (unsigned)ei[e];
                unsigned d = (unsigned)ei[NE + e];
                pk[j] = (d << 16) | s;             // bucket = pk >> 22 (BS=64)
                atomicAdd(&hist[pk[j] >> 22], 1);
            }
        }
        __syncthreads();
        // pair-wise wave shfl scan over 782 bins (thread t owns bins 2t,2t+1)
        const int i0 = 2 * t, i1 = 2 * t + 1;
        int h0 = (i0 < NB) ? hist[i0] : 0;
        int h1 = (i1 < NB) ? hist[i1] : 0;
        int v = wscan(h0 + h1);
        if (lane == 63) wsum[w] = v;
        __syncthreads();
        int addv = 0;
        #pragma unroll
        for (int i = 0; i < 8; ++i) addv += (i < w) ? wsum[i] : 0;
        v += addv;                                 // inclusive through bin i1
        int ex1 = v - h1, ex0 = ex1 - h0;          // exclusive bases
        if (i0 < NB) { cur[i0] = ex0; offs[i0 * NSB + blk] = (ushort)ex0; }
        if (i1 < NB) { cur[i1] = ex1; offs[i1 * NSB + blk] = (ushort)ex1; }
        if (t == 0) offs[NB * NSB + blk] = (ushort)cnt;
        __syncthreads();
        #pragma unroll
        for (int j = 0; j < 8; ++j) {
            int idx = j * 512 + t;
            if (idx < cnt) {
                int l = atomicAdd(&cur[pk[j] >> 22], 1);
                spk[l] = pk[j];
            }
        }
        __syncthreads();
        for (int i = t; i < cnt; i += 512)         // dense coalesced 16KB
            buf[(size_t)blk * EPB + i] = spk[i];
    } else {
        // prep branch: bf16 conversion
        int i = (blockIdx.x - NSB) * 512 + t;
        if (i < NF4) {
            float4 v = ((const float4*)nf)[i];
            ((ushort4*)nfh)[i] = make_ushort4(f2bf(v.x), f2bf(v.y), f2bf(v.z), f2bf(v.w));
        } else if (i < NF4 + W4) {
            int k = i - NF4;
            float4 v = ((const float4*)W)[k];
            ((ushort4*)Wh)[k] = make_ushort4(f2bf(v.x), f2bf(v.y), f2bf(v.z), f2bf(v.w));
        }
    }
}

// ---- 2. fused gather-sort + aggregate + linear ----------------------------
__global__ __launch_bounds__(512, 4) void k_sort_agg(
    const unsigned* __restrict__ nfh, const unsigned* __restrict__ buf,
    const ushort* __restrict__ offs, const ushort* __restrict__ Wh,
    const float* __restrict__ bias, float* __restrict__ out)
{
    __shared__ ushort srt[CAP];                     // 4096 B
    __shared__ int scnt[256];                       // 1024 B
    __shared__ int sbase[NSB], rbase[NSB];          // 1568 B
    __shared__ int hist[BS], off[BS], cur[BS];      // 768 B
    __shared__ int wred[16];
    __shared__ __align__(16) unsigned tile[BS * AROWU / 2];  // 17408 B
    __shared__ __align__(16) unsigned stag[8][1024];         // 32768 B ring
    const int b = blockIdx.x, t = threadIdx.x;
    const int lane = t & 63, w = t >> 6;

    // --- Phase A1: per-producer run bases/counts -> wave shfl scan
    int my = 0;
    if (t < NSB) {
        int o0 = (int)offs[b * NSB + t];           // coalesced row
        int o1 = (int)offs[(b + 1) * NSB + t];
        rbase[t] = o0;
        my = o1 - o0;
    }
    if (t < BS) hist[t] = 0;
    int vs = 0;
    if (w < 4) {
        vs = wscan(my);
        if (lane == 63) wred[w] = vs;
    }
    __syncthreads();
    if (w < 4) {
        int addv = 0;
        #pragma unroll
        for (int i = 0; i < 3; ++i) addv += (i < w) ? wred[i] : 0;
        vs += addv;
        scnt[t] = vs;                              // global inclusive
        if (t < NSB) sbase[t] = vs - my;
    }
    __syncthreads();
    int total = scnt[NSB - 1];
    if (total > CAP) total = CAP;                  // defensive

    // --- Phase A2: pk in registers + node histogram
    unsigned mypk[4];
    int mycnt = 0;
    #pragma unroll
    for (int j = 0; j < 4; ++j) {
        int p = t + j * 512;
        if (p < total) {
            int lo = 0, hi = NSB - 1;              // min i: scnt[i] > p
            while (lo < hi) {
                int mid = (lo + hi) >> 1;
                if (scnt[mid] > p) hi = mid; else lo = mid + 1;
            }
            unsigned pk = buf[(size_t)lo * EPB + rbase[lo] + (p - sbase[lo])];
            mypk[j] = pk;
            atomicAdd(&hist[(pk >> 16) & (BS - 1)], 1);
            mycnt = j + 1;
        }
    }
    __syncthreads();

    // --- Phase A3: 64-bin scan (single wave) + scatter into srt (local CSR)
    int hv = (t < BS) ? hist[t] : 0;
    int nv = 0;
    if (w == 0) nv = wscan(hv);
    __syncthreads();
    if (t < BS) { int ex = nv - hv; off[t] = ex; cur[t] = ex; }
    __syncthreads();
    #pragma unroll
    for (int j = 0; j < 4; ++j) {
        if (j < mycnt) {
            unsigned pk = mypk[j];
            int n = (pk >> 16) & (BS - 1);
            int p = atomicAdd(&cur[n], 1);
            srt[p] = (ushort)(pk & 0xffffu);
        }
    }
    __syncthreads();

    // --- Phase B: async-staged streaming gather over the wave's 8-node
    // contiguous CSR segment. Chunk = 8 edges = 2 x global_load_lds_dwordx4.
    // Depth-2 ring in stag[w] (16 slots x 256B). Counted vmcnt, never 0
    // mid-loop. Consume: 64 lanes x ds_read_b32 -> 2 dims/lane.
    const int qw = lane >> 4;                      // edge-of-4 within instr
    const int slw = lane & 15;                     // 16B slot within row
    const unsigned* nfu = nfh;                     // row = 64 uints
    unsigned* stagw = stag[w];

    const int wbeg = off[w * 8];
    const int wend = (w < 7) ? off[w * 8 + 8] : total;
    const int nq = wend - wbeg;
    const int nc = (nq + 7) >> 3;

    auto ISSUE = [&](int c) {
        const int half = (c & 1) * 512;            // uints (2KB)
        #pragma unroll
        for (int j = 0; j < 2; ++j) {
            int e = wbeg + c * 8 + j * 4 + qw;
            if (e >= wend) e = wbeg;               // clamp (never consumed)
            const unsigned* g = nfu + (size_t)srt[e] * 64 + slw * 4;
            gl_lds16(g, stagw + half + j * 256);
        }
    };
    auto ENDR = [&](int cn_) -> int {              // end of node cn_ (rel)
        int n1 = w * 8 + cn_ + 1;
        return ((n1 < BS) ? off[n1] : total) - wbeg;
    };

    f32x2 acc = {0.f, 0.f};
    int cn = 0;
    int cend = ENDR(0);

    if (nc > 0) {
        ISSUE(0);
        if (nc > 1) ISSUE(1);
        for (int c = 0; c < nc; ++c) {
            if (c + 1 < nc) { WAITVM2(); } else { WAITVM0(); }
            int kmax = nq - 8 * c; if (kmax > 8) kmax = 8;
            for (int k = 0; k < kmax; ++k) {
                int p = 8 * c + k;
                while (cn < 7 && p >= cend) {      // flush finished nodes
                    tile[(w * 8 + cn) * (AROWU / 2) + lane] =
                        (unsigned)f2bf(acc.x) | ((unsigned)f2bf(acc.y) << 16);
                    acc.x = 0.f; acc.y = 0.f;
                    ++cn; cend = ENDR(cn);
                }
                unsigned u = stagw[((p & 15) << 6) + lane];
                acc.x += bflo(u); acc.y += bfhi(u);
            }
            if (c + 2 < nc) ISSUE(c + 2);
        }
    }
    // flush current node + trailing empty nodes
    tile[(w * 8 + cn) * (AROWU / 2) + lane] =
        (unsigned)f2bf(acc.x) | ((unsigned)f2bf(acc.y) << 16);
    for (int z = cn + 1; z < 8; ++z)
        tile[(w * 8 + z) * (AROWU / 2) + lane] = 0u;
    __syncthreads();

    // --- Phase C: 4 row-tiles x 8 col-chunks = 32 MFMA tasks over 8 waves
    const int m = lane & 15, q = lane >> 4;
    const ushort* lds = (const ushort*)tile;
    #pragma unroll
    for (int i = 0; i < 4; ++i) {
        const int task = w + 8 * i;                 // 0..31, bijective
        const int t16  = task >> 3;                 // row-tile 0..3
        const int c0   = (task & 7) * 16;           // col chunk
        const int grow0 = b * BS + t16 * 16;
        if (grow0 < NN) {                           // last bucket: 1 full tile
            bf16x8 a[4];
            const ushort* arow = lds + (t16 * 16 + m) * AROWU + q * 8;
            #pragma unroll
            for (int kk = 0; kk < 4; ++kk)
                a[kk] = *(const bf16x8*)(arow + kk * 32);
            float bv = bias[c0 + m];
            f32x4 acc4 = { bv, bv, bv, bv };
            const ushort* wrow = Wh + (size_t)(c0 + m) * D + q * 8;
            #pragma unroll
            for (int kk = 0; kk < 4; ++kk) {
                bf16x8 bb = *(const bf16x8*)(wrow + kk * 32);
                acc4 = __builtin_amdgcn_mfma_f32_16x16x32_bf16(a[kk], bb, acc4, 0, 0, 0);
            }
            float* op = out + (size_t)(grow0 + q * 4) * D + c0 + m;
            op[0]     = acc4[0];
            op[D]     = acc4[1];
            op[2 * D] = acc4[2];
            op[3 * D] = acc4[3];
        }
    }
}

extern "C" void kernel_launch(void* const* d_in, const int* in_sizes, int n_in,
                              void* d_out, int out_size, void* d_ws, size_t ws_size,
                              hipStream_t stream) {
    const float* nf = (const float*)d_in[0];
    const int*   ei = (const int*)d_in[1];
    const float* W  = (const float*)d_in[2];
    const float* b  = (const float*)d_in[3];
    float* out = (float*)d_out;

    // workspace (~16.4 MB)
    ushort*   nfh  = (ushort*)d_ws;                    // NN*D bf16 = 12.8 MB
    ushort*   Wh   = nfh + (size_t)NN * D;             // 32 KB
    unsigned* buf  = (unsigned*)(Wh + D * D);          // NSB*EPB u32 = 3.2 MB
    ushort*   offs = (ushort*)(buf + (size_t)NSB * EPB); // (NB+1)*NSB = 307 KB

    k_prep_bucket<<<GRID_A, 512, 0, stream>>>(nf, W, ei, nfh, Wh, offs, buf);
    k_sort_agg   <<<NB, 512, 0, stream>>>((const unsigned*)nfh, buf, offs, Wh, b, out);
}

// Round 6
// 128.347 us; speedup vs baseline: 1.1714x; 1.1714x over previous
//
#include <hip/hip_runtime.h>

// GNN layer: out = segment_sum(nf[src], dst) @ W.T + b
// N=50000, E=800000, D=128.
// R19: load-balance attack. R18 post-mortem: serial per-edge consume + 4KB
// in-flight regressed (74us). R14 (48.5us) remains best; model fit across
// R13-R18: gather is per-CU outstanding-miss x latency bound (~100 lines in
// flight @ ~600cy). Untouched lever: 391 blocks on 256 CUs -> 135 CUs carry
// 4096 edges, 121 carry 2048 (makespan prop. 4096 vs balanced 3125). Any
// grid <= residency*256 is statically assigned (co-resident), so BS=64/782
// would keep the tail. Fix: BS=32 -> 1563 blocks of 512 thr (residency 4/CU
// = 1024 < 1563) -> dynamic queue balancing, makespan ~3400 edges/CU.
// Phase B = proven R14 per-quarter uint4 walk, 1 node/quarter. 14KB LDS,
// no VGPR cap (launch_bounds(512) only) -> no silent spills, up to 32
// waves/CU. Producer scan generalized to 4 bins/thread (NB=1563).

constexpr int NN = 50000;
constexpr int NE = 800000;
constexpr int D  = 128;

constexpr int BS   = 32;                       // nodes per bucket
constexpr int NB   = (NN + BS - 1) / BS;       // 1563 buckets
constexpr int EPB  = 4096;                     // edges per producer block
constexpr int NSB  = (NE + EPB - 1) / EPB;     // 196 producer blocks
constexpr int CAP  = 1024;                     // per-bucket edge cap (avg 512)

constexpr int AROWU = 136;                     // tile row stride (ushorts)

typedef __attribute__((ext_vector_type(8))) short bf16x8;
typedef __attribute__((ext_vector_type(4))) float f32x4;
typedef __attribute__((ext_vector_type(2))) float f32x2;

__device__ inline unsigned short f2bf(float f) {           // RNE
    unsigned u = __float_as_uint(f);
    return (unsigned short)((u + 0x7fffu + ((u >> 16) & 1u)) >> 16);
}
__device__ inline float bflo(unsigned v) { return __uint_as_float(v << 16); }
__device__ inline float bfhi(unsigned v) { return __uint_as_float(v & 0xffff0000u); }

__device__ inline int wscan(int v) {           // wave-inclusive scan (64)
    #pragma unroll
    for (int o = 1; o < 64; o <<= 1) {
        int u = __shfl_up(v, o);
        if ((int)(threadIdx.x & 63) >= o) v += u;
    }
    return v;
}

__device__ inline void acc8(f32x2& a0, f32x2& a1, f32x2& a2, f32x2& a3, uint4 v) {
    a0 += (f32x2){bflo(v.x), bfhi(v.x)};
    a1 += (f32x2){bflo(v.y), bfhi(v.y)};
    a2 += (f32x2){bflo(v.z), bfhi(v.z)};
    a3 += (f32x2){bflo(v.w), bfhi(v.w)};
}

// ---- 1. fused prep (bf16 cvt) + bucket-sort partition ---------------------
constexpr int NF4 = NN * D / 4;                           // 1,600,000
constexpr int W4  = D * D / 4;                            // 4,096
constexpr int NBLK_P = (NF4 + W4 + 511) / 512;            // 3134
constexpr int GRID_A = NSB + NBLK_P;

__global__ __launch_bounds__(512) void k_prep_bucket(
    const float* __restrict__ nf, const float* __restrict__ W,
    const int* __restrict__ ei,
    ushort* __restrict__ nfh, ushort* __restrict__ Wh,
    ushort* __restrict__ offs, unsigned* __restrict__ buf)
{
    __shared__ int hist[NB], cur[NB];              // 12.5 KB
    __shared__ int wsum[8];
    __shared__ unsigned spk[EPB];                  // 16384 B
    const int t = threadIdx.x, lane = t & 63, w = t >> 6;

    if (blockIdx.x < NSB) {
        const int blk = blockIdx.x;
        const int e0  = blk * EPB;
        int cnt = NE - e0; if (cnt > EPB) cnt = EPB;

        for (int i = t; i < NB; i += 512) hist[i] = 0;
        __syncthreads();

        unsigned pk[8];
        #pragma unroll
        for (int j = 0; j < 8; ++j) {
            int idx = j * 512 + t;
            if (idx < cnt) {
                int e = e0 + idx;
                unsigned s = (unsigned)ei[e];
                unsigned d = (unsigned)ei[NE + e];
                pk[j] = (d << 16) | s;             // bucket = pk >> 21 (BS=32)
                atomicAdd(&hist[pk[j] >> 21], 1);
            }
        }
        __syncthreads();
        // 4-bins/thread wave shfl scan over 1563 bins
        const int base = 4 * t;
        int h0 = (base     < NB) ? hist[base]     : 0;
        int h1 = (base + 1 < NB) ? hist[base + 1] : 0;
        int h2 = (base + 2 < NB) ? hist[base + 2] : 0;
        int h3 = (base + 3 < NB) ? hist[base + 3] : 0;
        int s4 = h0 + h1 + h2 + h3;
        int v = wscan(s4);
        if (lane == 63) wsum[w] = v;
        __syncthreads();
        int addv = 0;
        #pragma unroll
        for (int i = 0; i < 8; ++i) addv += (i < w) ? wsum[i] : 0;
        v += addv;                                 // inclusive through base+3
        int e0b = v - s4, e1b = e0b + h0, e2b = e1b + h1, e3b = e2b + h2;
        if (base     < NB) { cur[base]     = e0b; offs[(base    ) * NSB + blk] = (ushort)e0b; }
        if (base + 1 < NB) { cur[base + 1] = e1b; offs[(base + 1) * NSB + blk] = (ushort)e1b; }
        if (base + 2 < NB) { cur[base + 2] = e2b; offs[(base + 2) * NSB + blk] = (ushort)e2b; }
        if (base + 3 < NB) { cur[base + 3] = e3b; offs[(base + 3) * NSB + blk] = (ushort)e3b; }
        if (t == 0) offs[NB * NSB + blk] = (ushort)cnt;
        __syncthreads();
        #pragma unroll
        for (int j = 0; j < 8; ++j) {
            int idx = j * 512 + t;
            if (idx < cnt) {
                int l = atomicAdd(&cur[pk[j] >> 21], 1);
                spk[l] = pk[j];
            }
        }
        __syncthreads();
        for (int i = t; i < cnt; i += 512)         // dense coalesced 16KB
            buf[(size_t)blk * EPB + i] = spk[i];
    } else {
        // prep branch: bf16 conversion
        int i = (blockIdx.x - NSB) * 512 + t;
        if (i < NF4) {
            float4 v = ((const float4*)nf)[i];
            ((ushort4*)nfh)[i] = make_ushort4(f2bf(v.x), f2bf(v.y), f2bf(v.z), f2bf(v.w));
        } else if (i < NF4 + W4) {
            int k = i - NF4;
            float4 v = ((const float4*)W)[k];
            ((ushort4*)Wh)[k] = make_ushort4(f2bf(v.x), f2bf(v.y), f2bf(v.z), f2bf(v.w));
        }
    }
}

// ---- 2. fused gather-sort + aggregate + linear ----------------------------
__global__ __launch_bounds__(512) void k_sort_agg(
    const unsigned* __restrict__ nfh, const unsigned* __restrict__ buf,
    const ushort* __restrict__ offs, const ushort* __restrict__ Wh,
    const float* __restrict__ bias, float* __restrict__ out)
{
    __shared__ ushort srt[CAP];                     // 2048 B
    __shared__ int scnt[256];                       // 1024 B
    __shared__ int sbase[NSB], rbase[NSB];          // 1568 B
    __shared__ int hist[BS], off[BS], cur[BS];      // 384 B
    __shared__ int wred[16];
    __shared__ __align__(16) unsigned tile[BS * AROWU / 2];  // 8704 B (~14KB)
    const int b = blockIdx.x, t = threadIdx.x;
    const int lane = t & 63, w = t >> 6;

    // --- Phase A1: per-producer run bases/counts -> wave shfl scan
    int my = 0;
    if (t < NSB) {
        int o0 = (int)offs[b * NSB + t];           // coalesced 392B row
        int o1 = (int)offs[(b + 1) * NSB + t];
        rbase[t] = o0;
        my = o1 - o0;
    }
    if (t < BS) hist[t] = 0;
    int vs = 0;
    if (w < 4) {
        vs = wscan(my);
        if (lane == 63) wred[w] = vs;
    }
    __syncthreads();
    if (w < 4) {
        int addv = 0;
        #pragma unroll
        for (int i = 0; i < 3; ++i) addv += (i < w) ? wred[i] : 0;
        vs += addv;
        scnt[t] = vs;                              // global inclusive
        if (t < NSB) sbase[t] = vs - my;
    }
    __syncthreads();
    int total = scnt[NSB - 1];
    if (total > CAP) total = CAP;                  // defensive

    // --- Phase A2: pk in registers + node histogram
    unsigned mypk[2];
    int mycnt = 0;
    #pragma unroll
    for (int j = 0; j < 2; ++j) {
        int p = t + j * 512;
        if (p < total) {
            int lo = 0, hi = NSB - 1;              // min i: scnt[i] > p
            while (lo < hi) {
                int mid = (lo + hi) >> 1;
                if (scnt[mid] > p) hi = mid; else lo = mid + 1;
            }
            unsigned pk = buf[(size_t)lo * EPB + rbase[lo] + (p - sbase[lo])];
            mypk[j] = pk;
            atomicAdd(&hist[(pk >> 16) & (BS - 1)], 1);
            mycnt = j + 1;
        }
    }
    __syncthreads();

    // --- Phase A3: 32-bin scan (single wave) + scatter into srt (local CSR)
    int hv = (t < BS) ? hist[t] : 0;
    int nv = 0;
    if (w == 0) nv = wscan(hv);
    __syncthreads();
    if (t < BS) { int ex = nv - hv; off[t] = ex; cur[t] = ex; }
    __syncthreads();
    #pragma unroll
    for (int j = 0; j < 2; ++j) {
        if (j < mycnt) {
            unsigned pk = mypk[j];
            int n = (pk >> 16) & (BS - 1);
            int p = atomicAdd(&cur[n], 1);
            srt[p] = (ushort)(pk & 0xffffu);
        }
    }
    __syncthreads();

    // --- Phase B: per-quarter node ownership (R14-proven), 1 node/quarter.
    // quarter qq owns node n = w*4 + qq; 16 lanes x uint4 = full 256B row.
    const int qq = lane >> 4;
    const int sl = lane & 15;
    const uint4* nfv = (const uint4*)nfh;          // row = idx*16 uint4s

    {
        const int n = w * 4 + qq;
        const int beg = off[n], cnt = hist[n];
        f32x2 a0 = {0.f, 0.f}, a1 = {0.f, 0.f}, a2 = {0.f, 0.f}, a3 = {0.f, 0.f};
        int p = 0;
        for (; p + 2 <= cnt; p += 2) {             // 2 gathers in flight
            const int s0 = srt[beg + p];
            const int s1 = srt[beg + p + 1];
            const uint4 v0 = nfv[(size_t)s0 * 16 + sl];
            const uint4 v1 = nfv[(size_t)s1 * 16 + sl];
            acc8(a0, a1, a2, a3, v0);
            acc8(a0, a1, a2, a3, v1);
        }
        if (p < cnt) {                             // odd tail
            const int s0 = srt[beg + p];
            const uint4 v0 = nfv[(size_t)s0 * 16 + sl];
            acc8(a0, a1, a2, a3, v0);
        }
        uint4 o;                                   // all 64 lanes: 4 rows/wave
        o.x = (unsigned)f2bf(a0.x) | ((unsigned)f2bf(a0.y) << 16);
        o.y = (unsigned)f2bf(a1.x) | ((unsigned)f2bf(a1.y) << 16);
        o.z = (unsigned)f2bf(a2.x) | ((unsigned)f2bf(a2.y) << 16);
        o.w = (unsigned)f2bf(a3.x) | ((unsigned)f2bf(a3.y) << 16);
        *(uint4*)(tile + n * (AROWU / 2) + sl * 4) = o;
    }
    __syncthreads();

    // --- Phase C: 2 row-tiles x 8 col-chunks = 16 MFMA tasks over 8 waves
    const int m = lane & 15, q = lane >> 4;
    const ushort* lds = (const ushort*)tile;
    #pragma unroll
    for (int i = 0; i < 2; ++i) {
        const int task = w + 8 * i;                 // 0..15, bijective
        const int t16  = task >> 3;                 // row-tile 0..1
        const int c0   = (task & 7) * 16;           // col chunk
        const int grow0 = b * BS + t16 * 16;
        if (grow0 < NN) {                           // last bucket: 1 full tile
            bf16x8 a[4];
            const ushort* arow = lds + (t16 * 16 + m) * AROWU + q * 8;
            #pragma unroll
            for (int kk = 0; kk < 4; ++kk)
                a[kk] = *(const bf16x8*)(arow + kk * 32);
            float bv = bias[c0 + m];
            f32x4 acc4 = { bv, bv, bv, bv };
            const ushort* wrow = Wh + (size_t)(c0 + m) * D + q * 8;
            #pragma unroll
            for (int kk = 0; kk < 4; ++kk) {
                bf16x8 bb = *(const bf16x8*)(wrow + kk * 32);
                acc4 = __builtin_amdgcn_mfma_f32_16x16x32_bf16(a[kk], bb, acc4, 0, 0, 0);
            }
            float* op = out + (size_t)(grow0 + q * 4) * D + c0 + m;
            op[0]     = acc4[0];
            op[D]     = acc4[1];
            op[2 * D] = acc4[2];
            op[3 * D] = acc4[3];
        }
    }
}

extern "C" void kernel_launch(void* const* d_in, const int* in_sizes, int n_in,
                              void* d_out, int out_size, void* d_ws, size_t ws_size,
                              hipStream_t stream) {
    const float* nf = (const float*)d_in[0];
    const int*   ei = (const int*)d_in[1];
    const float* W  = (const float*)d_in[2];
    const float* b  = (const float*)d_in[3];
    float* out = (float*)d_out;

    // workspace (~16.7 MB)
    ushort*   nfh  = (ushort*)d_ws;                    // NN*D bf16 = 12.8 MB
    ushort*   Wh   = nfh + (size_t)NN * D;             // 32 KB
    unsigned* buf  = (unsigned*)(Wh + D * D);          // NSB*EPB u32 = 3.2 MB
    ushort*   offs = (ushort*)(buf + (size_t)NSB * EPB); // (NB+1)*NSB = 613 KB

    k_prep_bucket<<<GRID_A, 512, 0, stream>>>(nf, W, ei, nfh, Wh, offs, buf);
    k_sort_agg   <<<NB, 512, 0, stream>>>((const unsigned*)nfh, buf, offs, Wh, b, out);
}

// Round 7
// 126.707 us; speedup vs baseline: 1.1866x; 1.0129x over previous
//
#include <hip/hip_runtime.h>

// GNN layer: out = segment_sum(nf[src], dst) @ W.T + b
// N=50000, E=800000, D=128.
// R20: co-residency attack. R19 post-mortem: balance worked (sort 48.5->45,
// occ 43->54%) but gains eaten by +12% FETCH (87MB, smaller-bucket reuse
// loss, compulsory-ish) and by A-phase fixed cost x4 more blocks. Stable
// identity: dur ~= sort_agg + 81us, so sort gains are 1:1. Remaining
// inefficiency: 512-thr blocks cap residency at 4 blocks/CU (wave slots),
// so during a block's barrier-heavy A/C phases the MSHR window drains.
// Fix: 256-thr consumer blocks -> 8 co-resident blocks/CU (32 waves, all
// slots), sibling blocks' Phase-B gathers overlap each other's A-phase
// latency chains. Phase code unchanged from proven R19/R14 patterns:
// B = per-quarter uint4 walk, 2 nodes/quarter (R14's i-loop); C = 4 MFMA
// tasks/wave. Producer unchanged.

constexpr int NN = 50000;
constexpr int NE = 800000;
constexpr int D  = 128;

constexpr int BS   = 32;                       // nodes per bucket
constexpr int NB   = (NN + BS - 1) / BS;       // 1563 buckets
constexpr int EPB  = 4096;                     // edges per producer block
constexpr int NSB  = (NE + EPB - 1) / EPB;     // 196 producer blocks
constexpr int CAP  = 1024;                     // per-bucket edge cap (avg 512)

constexpr int AROWU = 136;                     // tile row stride (ushorts)

typedef __attribute__((ext_vector_type(8))) short bf16x8;
typedef __attribute__((ext_vector_type(4))) float f32x4;
typedef __attribute__((ext_vector_type(2))) float f32x2;

__device__ inline unsigned short f2bf(float f) {           // RNE
    unsigned u = __float_as_uint(f);
    return (unsigned short)((u + 0x7fffu + ((u >> 16) & 1u)) >> 16);
}
__device__ inline float bflo(unsigned v) { return __uint_as_float(v << 16); }
__device__ inline float bfhi(unsigned v) { return __uint_as_float(v & 0xffff0000u); }

__device__ inline int wscan(int v) {           // wave-inclusive scan (64)
    #pragma unroll
    for (int o = 1; o < 64; o <<= 1) {
        int u = __shfl_up(v, o);
        if ((int)(threadIdx.x & 63) >= o) v += u;
    }
    return v;
}

__device__ inline void acc8(f32x2& a0, f32x2& a1, f32x2& a2, f32x2& a3, uint4 v) {
    a0 += (f32x2){bflo(v.x), bfhi(v.x)};
    a1 += (f32x2){bflo(v.y), bfhi(v.y)};
    a2 += (f32x2){bflo(v.z), bfhi(v.z)};
    a3 += (f32x2){bflo(v.w), bfhi(v.w)};
}

// ---- 1. fused prep (bf16 cvt) + bucket-sort partition ---------------------
constexpr int NF4 = NN * D / 4;                           // 1,600,000
constexpr int W4  = D * D / 4;                            // 4,096
constexpr int NBLK_P = (NF4 + W4 + 511) / 512;            // 3134
constexpr int GRID_A = NSB + NBLK_P;

__global__ __launch_bounds__(512) void k_prep_bucket(
    const float* __restrict__ nf, const float* __restrict__ W,
    const int* __restrict__ ei,
    ushort* __restrict__ nfh, ushort* __restrict__ Wh,
    ushort* __restrict__ offs, unsigned* __restrict__ buf)
{
    __shared__ int hist[NB], cur[NB];              // 12.5 KB
    __shared__ int wsum[8];
    __shared__ unsigned spk[EPB];                  // 16384 B
    const int t = threadIdx.x, lane = t & 63, w = t >> 6;

    if (blockIdx.x < NSB) {
        const int blk = blockIdx.x;
        const int e0  = blk * EPB;
        int cnt = NE - e0; if (cnt > EPB) cnt = EPB;

        for (int i = t; i < NB; i += 512) hist[i] = 0;
        __syncthreads();

        unsigned pk[8];
        #pragma unroll
        for (int j = 0; j < 8; ++j) {
            int idx = j * 512 + t;
            if (idx < cnt) {
                int e = e0 + idx;
                unsigned s = (unsigned)ei[e];
                unsigned d = (unsigned)ei[NE + e];
                pk[j] = (d << 16) | s;             // bucket = pk >> 21 (BS=32)
                atomicAdd(&hist[pk[j] >> 21], 1);
            }
        }
        __syncthreads();
        // 4-bins/thread wave shfl scan over 1563 bins
        const int base = 4 * t;
        int h0 = (base     < NB) ? hist[base]     : 0;
        int h1 = (base + 1 < NB) ? hist[base + 1] : 0;
        int h2 = (base + 2 < NB) ? hist[base + 2] : 0;
        int h3 = (base + 3 < NB) ? hist[base + 3] : 0;
        int s4 = h0 + h1 + h2 + h3;
        int v = wscan(s4);
        if (lane == 63) wsum[w] = v;
        __syncthreads();
        int addv = 0;
        #pragma unroll
        for (int i = 0; i < 8; ++i) addv += (i < w) ? wsum[i] : 0;
        v += addv;                                 // inclusive through base+3
        int e0b = v - s4, e1b = e0b + h0, e2b = e1b + h1, e3b = e2b + h2;
        if (base     < NB) { cur[base]     = e0b; offs[(base    ) * NSB + blk] = (ushort)e0b; }
        if (base + 1 < NB) { cur[base + 1] = e1b; offs[(base + 1) * NSB + blk] = (ushort)e1b; }
        if (base + 2 < NB) { cur[base + 2] = e2b; offs[(base + 2) * NSB + blk] = (ushort)e2b; }
        if (base + 3 < NB) { cur[base + 3] = e3b; offs[(base + 3) * NSB + blk] = (ushort)e3b; }
        if (t == 0) offs[NB * NSB + blk] = (ushort)cnt;
        __syncthreads();
        #pragma unroll
        for (int j = 0; j < 8; ++j) {
            int idx = j * 512 + t;
            if (idx < cnt) {
                int l = atomicAdd(&cur[pk[j] >> 21], 1);
                spk[l] = pk[j];
            }
        }
        __syncthreads();
        for (int i = t; i < cnt; i += 512)         // dense coalesced 16KB
            buf[(size_t)blk * EPB + i] = spk[i];
    } else {
        // prep branch: bf16 conversion
        int i = (blockIdx.x - NSB) * 512 + t;
        if (i < NF4) {
            float4 v = ((const float4*)nf)[i];
            ((ushort4*)nfh)[i] = make_ushort4(f2bf(v.x), f2bf(v.y), f2bf(v.z), f2bf(v.w));
        } else if (i < NF4 + W4) {
            int k = i - NF4;
            float4 v = ((const float4*)W)[k];
            ((ushort4*)Wh)[k] = make_ushort4(f2bf(v.x), f2bf(v.y), f2bf(v.z), f2bf(v.w));
        }
    }
}

// ---- 2. fused gather-sort + aggregate + linear ----------------------------
__global__ __launch_bounds__(256, 8) void k_sort_agg(
    const unsigned* __restrict__ nfh, const unsigned* __restrict__ buf,
    const ushort* __restrict__ offs, const ushort* __restrict__ Wh,
    const float* __restrict__ bias, float* __restrict__ out)
{
    __shared__ ushort srt[CAP];                     // 2048 B
    __shared__ int scnt[256];                       // 1024 B
    __shared__ int sbase[NSB], rbase[NSB];          // 1568 B
    __shared__ int hist[BS], off[BS], cur[BS];      // 384 B
    __shared__ int wred[16];
    __shared__ __align__(16) unsigned tile[BS * AROWU / 2];  // 8704 B (~14KB)
    const int b = blockIdx.x, t = threadIdx.x;
    const int lane = t & 63, w = t >> 6;           // 4 waves

    // --- Phase A1: per-producer run bases/counts -> wave shfl scan
    int my = 0;
    if (t < NSB) {
        int o0 = (int)offs[b * NSB + t];           // coalesced 392B row
        int o1 = (int)offs[(b + 1) * NSB + t];
        rbase[t] = o0;
        my = o1 - o0;
    }
    if (t < BS) hist[t] = 0;
    int vs = wscan(my);
    if (lane == 63) wred[w] = vs;
    __syncthreads();
    {
        int addv = 0;
        #pragma unroll
        for (int i = 0; i < 3; ++i) addv += (i < w) ? wred[i] : 0;
        vs += addv;
        scnt[t] = vs;                              // global inclusive
        if (t < NSB) sbase[t] = vs - my;
    }
    __syncthreads();
    int total = scnt[NSB - 1];
    if (total > CAP) total = CAP;                  // defensive

    // --- Phase A2: pk in registers + node histogram
    unsigned mypk[4];
    int mycnt = 0;
    #pragma unroll
    for (int j = 0; j < 4; ++j) {
        int p = t + j * 256;
        if (p < total) {
            int lo = 0, hi = NSB - 1;              // min i: scnt[i] > p
            while (lo < hi) {
                int mid = (lo + hi) >> 1;
                if (scnt[mid] > p) hi = mid; else lo = mid + 1;
            }
            unsigned pk = buf[(size_t)lo * EPB + rbase[lo] + (p - sbase[lo])];
            mypk[j] = pk;
            atomicAdd(&hist[(pk >> 16) & (BS - 1)], 1);
            mycnt = j + 1;
        }
    }
    __syncthreads();

    // --- Phase A3: 32-bin scan (single wave) + scatter into srt (local CSR)
    int hv = (t < BS) ? hist[t] : 0;
    int nv = 0;
    if (w == 0) nv = wscan(hv);
    __syncthreads();
    if (t < BS) { int ex = nv - hv; off[t] = ex; cur[t] = ex; }
    __syncthreads();
    #pragma unroll
    for (int j = 0; j < 4; ++j) {
        if (j < mycnt) {
            unsigned pk = mypk[j];
            int n = (pk >> 16) & (BS - 1);
            int p = atomicAdd(&cur[n], 1);
            srt[p] = (ushort)(pk & 0xffffu);
        }
    }
    __syncthreads();

    // --- Phase B: per-quarter node ownership (R14-proven), 2 nodes/quarter.
    // quarter qq owns node n = w*8 + i*4 + qq; 16 lanes x uint4 = 256B row.
    const int qq = lane >> 4;
    const int sl = lane & 15;
    const uint4* nfv = (const uint4*)nfh;          // row = idx*16 uint4s

    #pragma unroll 1
    for (int i = 0; i < 2; ++i) {
        const int n = w * 8 + i * 4 + qq;
        const int beg = off[n], cnt = hist[n];
        f32x2 a0 = {0.f, 0.f}, a1 = {0.f, 0.f}, a2 = {0.f, 0.f}, a3 = {0.f, 0.f};
        int p = 0;
        for (; p + 2 <= cnt; p += 2) {             // 2 gathers in flight
            const int s0 = srt[beg + p];
            const int s1 = srt[beg + p + 1];
            const uint4 v0 = nfv[(size_t)s0 * 16 + sl];
            const uint4 v1 = nfv[(size_t)s1 * 16 + sl];
            acc8(a0, a1, a2, a3, v0);
            acc8(a0, a1, a2, a3, v1);
        }
        if (p < cnt) {                             // odd tail
            const int s0 = srt[beg + p];
            const uint4 v0 = nfv[(size_t)s0 * 16 + sl];
            acc8(a0, a1, a2, a3, v0);
        }
        uint4 o;                                   // all 64 lanes: 4 rows/wave
        o.x = (unsigned)f2bf(a0.x) | ((unsigned)f2bf(a0.y) << 16);
        o.y = (unsigned)f2bf(a1.x) | ((unsigned)f2bf(a1.y) << 16);
        o.z = (unsigned)f2bf(a2.x) | ((unsigned)f2bf(a2.y) << 16);
        o.w = (unsigned)f2bf(a3.x) | ((unsigned)f2bf(a3.y) << 16);
        *(uint4*)(tile + n * (AROWU / 2) + sl * 4) = o;
    }
    __syncthreads();

    // --- Phase C: 2 row-tiles x 8 col-chunks = 16 MFMA tasks over 4 waves
    const int m = lane & 15, q = lane >> 4;
    const ushort* lds = (const ushort*)tile;
    #pragma unroll
    for (int i = 0; i < 4; ++i) {
        const int task = w + 4 * i;                 // 0..15, bijective
        const int t16  = task >> 3;                 // row-tile 0..1
        const int c0   = (task & 7) * 16;           // col chunk
        const int grow0 = b * BS + t16 * 16;
        if (grow0 < NN) {                           // last bucket: 1 full tile
            bf16x8 a[4];
            const ushort* arow = lds + (t16 * 16 + m) * AROWU + q * 8;
            #pragma unroll
            for (int kk = 0; kk < 4; ++kk)
                a[kk] = *(const bf16x8*)(arow + kk * 32);
            float bv = bias[c0 + m];
            f32x4 acc4 = { bv, bv, bv, bv };
            const ushort* wrow = Wh + (size_t)(c0 + m) * D + q * 8;
            #pragma unroll
            for (int kk = 0; kk < 4; ++kk) {
                bf16x8 bb = *(const bf16x8*)(wrow + kk * 32);
                acc4 = __builtin_amdgcn_mfma_f32_16x16x32_bf16(a[kk], bb, acc4, 0, 0, 0);
            }
            float* op = out + (size_t)(grow0 + q * 4) * D + c0 + m;
            op[0]     = acc4[0];
            op[D]     = acc4[1];
            op[2 * D] = acc4[2];
            op[3 * D] = acc4[3];
        }
    }
}

extern "C" void kernel_launch(void* const* d_in, const int* in_sizes, int n_in,
                              void* d_out, int out_size, void* d_ws, size_t ws_size,
                              hipStream_t stream) {
    const float* nf = (const float*)d_in[0];
    const int*   ei = (const int*)d_in[1];
    const float* W  = (const float*)d_in[2];
    const float* b  = (const float*)d_in[3];
    float* out = (float*)d_out;

    // workspace (~16.7 MB)
    ushort*   nfh  = (ushort*)d_ws;                    // NN*D bf16 = 12.8 MB
    ushort*   Wh   = nfh + (size_t)NN * D;             // 32 KB
    unsigned* buf  = (unsigned*)(Wh + D * D);          // NSB*EPB u32 = 3.2 MB
    ushort*   offs = (ushort*)(buf + (size_t)NSB * EPB); // (NB+1)*NSB = 613 KB

    k_prep_bucket<<<GRID_A, 512, 0, stream>>>(nf, W, ei, nfh, Wh, offs, buf);
    k_sort_agg   <<<NB, 256, 0, stream>>>((const unsigned*)nfh, buf, offs, Wh, b, out);
}